// Round 5
// baseline (2497.198 us; speedup 1.0000x reference)
//
#include <hip/hip_runtime.h>
#include <math.h>

#define NPTS  10000
#define KNB   32
#define NCELL 216     // 6*6*6
#define NSGT  157     // ceil(NPTS/64) sort groups

// ---------------------------------------------------------------------------
// helpers
// ---------------------------------------------------------------------------
__device__ __forceinline__ float sgnf(float v) {
    return (v > 0.0f) ? 1.0f : ((v < 0.0f) ? -1.0f : 0.0f);
}

// Open3D ball->cube volume-preserving map, transcribed from the reference.
__device__ __forceinline__ void ball_to_cube(float x, float y, float z,
                                             float& X, float& Y, float& Z) {
    const float EPSF = 1e-12f;
    const float FOPI = (float)(4.0 / 3.14159265358979323846);
    float sq   = x * x + y * y + z * z;
    float norm = sqrtf(fmaxf(sq, EPSF));
    float rho2 = x * x + y * y;
    bool in_cone = (1.25f * z * z > rho2);
    float s1 = sqrtf(3.0f * norm / (norm + fabsf(z)));
    float s2 = norm / sqrtf(fmaxf(rho2, EPSF));
    float s  = in_cone ? s1 : s2;
    float xc = x * s;
    float yc = y * s;
    float zc = in_cone ? sgnf(z) * norm : 1.5f * z;
    if (sq < EPSF) { xc = 0.0f; yc = 0.0f; zc = 0.0f; }
    float sq_xy   = xc * xc + yc * yc;
    float norm_xy = sqrtf(fmaxf(sq_xy, EPSF));
    bool x_major = (fabsf(yc) <= fabsf(xc));
    float xd = (fabsf(xc) < EPSF) ? 1.0f : xc;
    float yd = (fabsf(yc) < EPSF) ? 1.0f : yc;
    float tx = sgnf(xc) * norm_xy;
    float ty = sgnf(yc) * norm_xy;
    float xq = x_major ? tx : ty * FOPI * atanf(xc / yd);
    float yq = x_major ? tx * FOPI * atanf(yc / xd) : ty;
    if (sq_xy < EPSF) { xq = 0.0f; yq = 0.0f; }
    X = xq; Y = yq; Z = zc;
}

// ---------------------------------------------------------------------------
// Kernel 1: per-(point,neighbor) geometry record + neighbor counts.
// Record (uint4): x,y,z = trilinear fracs (fp32 bits); w = packed:
//   [7:0]=c000 cell, [8]=dx?, [9]=dy?, [10]=dz?, [11]=valid, [25:12]=nidx
// ---------------------------------------------------------------------------
__global__ __launch_bounds__(256) void geom_kernel(
    const float* __restrict__ pos, const int* __restrict__ nidx,
    uint4* __restrict__ geo, float* __restrict__ cnt) {
    int t = blockIdx.x * 256 + threadIdx.x;
    if (t >= NPTS * KNB) return;
    int j = t >> 5;
    int k = t & 31;
    int nid = nidx[t];
    float px = pos[j * 3], py = pos[j * 3 + 1], pz = pos[j * 3 + 2];
    float qx = pos[nid * 3], qy = pos[nid * 3 + 1], qz = pos[nid * 3 + 2];
    // exact fp32 (no FMA contraction) to reproduce numpy's mask bit-for-bit
    float dx = __fsub_rn(px, qx), dy = __fsub_rn(py, qy), dz = __fsub_rn(pz, qz);
    float d2 = __fadd_rn(__fadd_rn(__fmul_rn(dx, dx), __fmul_rn(dy, dy)),
                         __fmul_rn(dz, dz));
    bool valid = (d2 <= 2.25f);
    if (valid && nid == 0) {
        for (int kk = 0; kk < k; ++kk) {
            if (nidx[j * KNB + kk] == 0) { valid = false; break; }
        }
    }
    uint4 g = make_uint4(0u, 0u, 0u, 0u);
    if (valid) {
        const float C = (float)(2.0 / 3.0);   // 2/EXTENT
        float ux = (qx - px) * C, uy = (qy - py) * C, uz = (qz - pz) * C;
        float X, Y, Z;
        ball_to_cube(ux, uy, uz, X, Y, Z);
        float cs[3] = { (X + 1.0f) * 2.5f, (Y + 1.0f) * 2.5f, (Z + 1.0f) * 2.5f };
        int i0[3], i1[3];
        float fr[3];
        #pragma unroll
        for (int d = 0; d < 3; ++d) {
            float f0 = floorf(cs[d]);
            fr[d] = cs[d] - f0;               // frac from UNCLIPPED floor (ref)
            int a = (int)f0;
            a = min(max(a, 0), 5);
            i0[d] = a;
            i1[d] = min(a + 1, 5);
        }
        int c000 = (i0[0] * 6 + i0[1]) * 6 + i0[2];
        unsigned bits = (unsigned)c000
                      | ((unsigned)(i1[0] - i0[0]) << 8)
                      | ((unsigned)(i1[1] - i0[1]) << 9)
                      | ((unsigned)(i1[2] - i0[2]) << 10)
                      | (1u << 11)
                      | ((unsigned)nid << 12);
        g.x = __float_as_uint(fr[0]);
        g.y = __float_as_uint(fr[1]);
        g.z = __float_as_uint(fr[2]);
        g.w = bits;
        atomicAdd(&cnt[j], 1.0f);
    }
    geo[t] = g;
}

// ---------------------------------------------------------------------------
// Kernel 2: counting sort of corner contributions by CELL per 64-pt sort
// group. Payload packs nid | ptl<<14 | cell<<20. starts[sg][217] = per-cell
// prefix. Built once, consumed by all 3 conv layers.
// ---------------------------------------------------------------------------
__global__ __launch_bounds__(256) void sort_kernel(
    const uint4* __restrict__ geo, uint2* __restrict__ contribs,
    int* __restrict__ starts) {
    __shared__ int hist[NCELL];
    __shared__ int pref[NCELL + 1];
    const int sg = blockIdx.x, tid = threadIdx.x;
    if (tid < NCELL) hist[tid] = 0;
    __syncthreads();
    const int npts = min(64, NPTS - sg * 64);
    const int nrec = npts * KNB;
    const uint4* gb = geo + (size_t)sg * 64 * KNB;
    for (int r = tid; r < nrec; r += 256) {
        uint4 g = gb[r];
        if (g.w & 2048u) {
            int c000 = g.w & 255u;
            int dxo = (g.w & 256u)  ? 36 : 0;
            int dyo = (g.w & 512u)  ? 6  : 0;
            int dzo = (g.w & 1024u) ? 1  : 0;
            #pragma unroll
            for (int c = 0; c < 8; ++c) {
                int cell = c000 + ((c & 4) ? dxo : 0) + ((c & 2) ? dyo : 0)
                                + ((c & 1) ? dzo : 0);
                atomicAdd(&hist[cell], 1);
            }
        }
    }
    __syncthreads();
    if (tid == 0) {
        int run = 0;
        for (int m = 0; m < NCELL; ++m) { pref[m] = run; run += hist[m]; }
        pref[NCELL] = run;
    }
    __syncthreads();
    for (int i = tid; i < NCELL + 1; i += 256)
        starts[sg * (NCELL + 1) + i] = pref[i];
    if (tid < NCELL) hist[tid] = pref[tid];   // cursors
    __syncthreads();
    uint2* cb = contribs + (size_t)sg * 16384;
    for (int r = tid; r < nrec; r += 256) {
        uint4 g = gb[r];
        if (g.w & 2048u) {
            int ptl = r >> 5;
            float fx = __uint_as_float(g.x);
            float fy = __uint_as_float(g.y);
            float fz = __uint_as_float(g.z);
            int c000 = g.w & 255u;
            int dxo = (g.w & 256u)  ? 36 : 0;
            int dyo = (g.w & 512u)  ? 6  : 0;
            int dzo = (g.w & 1024u) ? 1  : 0;
            int nid = (g.w >> 12) & 16383u;
            #pragma unroll
            for (int c = 0; c < 8; ++c) {
                float wgt = ((c & 4) ? fx : 1.f - fx)
                          * ((c & 2) ? fy : 1.f - fy)
                          * ((c & 1) ? fz : 1.f - fz);
                int cell = c000 + ((c & 4) ? dxo : 0) + ((c & 2) ? dyo : 0)
                                + ((c & 1) ? dzo : 0);
                int p = atomicAdd(&hist[cell], 1);
                cb[p] = make_uint2(__float_as_uint(wgt),
                                   (unsigned)nid | ((unsigned)ptl << 14)
                                                 | ((unsigned)cell << 20));
            }
        }
    }
}

// ---------------------------------------------------------------------------
// Kernel 3: conv as 2D-register-tiled GEMM.
// Block = 128 pts (2 sort groups) x COUT, 256 threads.
// Thread (ptg=tid>>3, cog=tid&7) owns a 4pt x (COUT/8)co tile.
//  - A (scattered features) in LDS, layout [pt][k] stride KC+4; per 4-k each
//    thread reads 4 per-lane-distinct b128 (8 cog lanes broadcast-merge).
//  - W read directly from GLOBAL as per-lane float4 vector loads (L1/L2
//    resident, vmcnt-pipelined) -- no SGPR serialization, no LDS traffic.
//  - Scatter is U=4 batched: 4 rec loads issue -> 1 wait -> 4 feat loads
//    issue -> 1 wait -> LDS atomics. Double-buffered A overlaps scatter(c+1)
//    with GEMM(c). K-split over blockIdx.y into partial buffers.
// ---------------------------------------------------------------------------
template<int CIN, int COUT, int CPC, int KSPLIT>
__global__ __launch_bounds__(256, 2) void conv_kernel(
    const float* __restrict__ feats, const float* __restrict__ W,
    const uint2* __restrict__ contribs, const int* __restrict__ starts,
    float* __restrict__ partial) {
    constexpr int KC   = CPC * CIN;       // K per chunk (32 or 64)
    constexpr int ASTR = KC + 4;          // row stride, mult of 4 (b128 ok)
    constexpr int NCHUNK = NCELL / CPC;
    constexpr int Q4   = COUT / 32;       // co float4s per thread (2 or 1)
    constexpr int TPC  = CIN / 4;         // threads per contribution
    constexpr int SLOT = 128 / TPC;       // scatter slots per sort group
    constexpr int U    = 4;               // scatter pipeline batch

    __shared__ alignas(16) float Ab[2][128 * ASTR];
    __shared__ int Sl[2][NCELL + 1];

    const int tid = threadIdx.x;
    const int ptg = tid >> 3;             // 0..31
    const int cog = tid & 7;              // 0..7
    const int bx  = blockIdx.x;
    const int ks  = blockIdx.y;

    // scatter role
    const int sgl   = tid >> 7;           // 0/1: which sort group
    const int lslot = (tid & 127) / TPC;
    const int ch    = tid % TPC;
    const uint2* cbs = contribs + (size_t)(bx * 2 + sgl) * 16384;

    for (int s2 = 0; s2 < 2; ++s2) {
        int sg = bx * 2 + s2;
        for (int i = tid; i < NCELL + 1; i += 256)
            Sl[s2][i] = (sg < NSGT) ? starts[sg * (NCELL + 1) + i] : 0;
    }

    const int c0 = NCHUNK * ks / KSPLIT;
    const int c1 = NCHUNK * (ks + 1) / KSPLIT;

    auto zero = [&](int b) {
        float4 z; z.x = z.y = z.z = z.w = 0.f;
        float4* p = reinterpret_cast<float4*>(Ab[b]);
        for (int i = tid; i < 128 * ASTR / 4; i += 256) p[i] = z;
    };
    auto scatter = [&](int c, int b) {
        const int cb = c * CPC;
        const int s = Sl[sgl][cb], e = Sl[sgl][cb + CPC];
        float* Abase = Ab[b] + sgl * 64 * ASTR;
        int i = s + lslot;
        while (i < e) {
            uint2 recs[U];
            #pragma unroll
            for (int u = 0; u < U; ++u) {
                int idx = i + u * SLOT;
                recs[u] = cbs[min(idx, e - 1)];     // all issue, one wait
            }
            float4 f4[U];
            #pragma unroll
            for (int u = 0; u < U; ++u) {
                int nid = recs[u].y & 16383;
                f4[u] = *reinterpret_cast<const float4*>(
                    feats + (size_t)nid * CIN + ch * 4);  // all issue, one wait
            }
            #pragma unroll
            for (int u = 0; u < U; ++u) {
                int idx = i + u * SLOT;
                if (idx < e) {
                    float wgt = __uint_as_float(recs[u].x);
                    int ptl = (recs[u].y >> 14) & 63;
                    int cel = (int)(recs[u].y >> 20);
                    float* dst = Abase + ptl * ASTR + (cel - cb) * CIN + ch * 4;
                    atomicAdd(dst + 0, wgt * f4[u].x);
                    atomicAdd(dst + 1, wgt * f4[u].y);
                    atomicAdd(dst + 2, wgt * f4[u].z);
                    atomicAdd(dst + 3, wgt * f4[u].w);
                }
            }
            i += U * SLOT;
        }
    };

    zero(0); zero(1);
    __syncthreads();                     // also publishes Sl
    scatter(c0, 0);
    __syncthreads();

    float4 acc[4][Q4];
    #pragma unroll
    for (int p = 0; p < 4; ++p)
        #pragma unroll
        for (int q = 0; q < Q4; ++q) { acc[p][q].x = acc[p][q].y = acc[p][q].z = acc[p][q].w = 0.f; }

    for (int c = c0; c < c1; ++c) {
        const int b = (c - c0) & 1;
        if (c + 1 < c1) scatter(c + 1, b ^ 1);   // overlaps GEMM below
        const float* Wc = W + (size_t)c * KC * COUT + cog * (Q4 * 4);
        const float* Ablk = Ab[b] + ptg * 4 * ASTR;
        #pragma unroll 2
        for (int g = 0; g < KC / 4; ++g) {
            float4 wv[4][Q4];                    // global vector loads, pipelined
            #pragma unroll
            for (int j = 0; j < 4; ++j) {
                const float* wp = Wc + (size_t)(g * 4 + j) * COUT;
                #pragma unroll
                for (int q = 0; q < Q4; ++q)
                    wv[j][q] = *reinterpret_cast<const float4*>(wp + q * 4);
            }
            float4 av[4];                        // per-lane-distinct LDS b128
            #pragma unroll
            for (int p = 0; p < 4; ++p)
                av[p] = *reinterpret_cast<const float4*>(Ablk + p * ASTR + g * 4);
            #pragma unroll
            for (int p = 0; p < 4; ++p) {
                const float* ap = reinterpret_cast<const float*>(&av[p]);
                #pragma unroll
                for (int j = 0; j < 4; ++j) {
                    float a = ap[j];
                    #pragma unroll
                    for (int q = 0; q < Q4; ++q) {
                        acc[p][q].x = fmaf(a, wv[j][q].x, acc[p][q].x);
                        acc[p][q].y = fmaf(a, wv[j][q].y, acc[p][q].y);
                        acc[p][q].z = fmaf(a, wv[j][q].z, acc[p][q].z);
                        acc[p][q].w = fmaf(a, wv[j][q].w, acc[p][q].w);
                    }
                }
            }
        }
        __syncthreads();
        zero(b);
        __syncthreads();
    }

    #pragma unroll
    for (int p = 0; p < 4; ++p) {
        int n = bx * 128 + ptg * 4 + p;
        if (n < NPTS) {
            float* po = partial + ((size_t)ks * NPTS + n) * COUT + cog * (Q4 * 4);
            #pragma unroll
            for (int q = 0; q < Q4; ++q)
                *reinterpret_cast<float4*>(po + q * 4) = acc[p][q];
        }
    }
}

// ---------------------------------------------------------------------------
// Kernel 4: combine K-split partials, normalize by neighbor count, bias, relu.
// ---------------------------------------------------------------------------
template<int COUT, int KSPLIT>
__global__ __launch_bounds__(256) void combine_kernel(
    const float* __restrict__ partial, const float* __restrict__ cnt,
    const float* __restrict__ bias, float* __restrict__ out) {
    int idx = blockIdx.x * 256 + threadIdx.x;
    if (idx >= NPTS * COUT) return;
    int n = idx / COUT, co = idx % COUT;
    float s = 0.f;
    #pragma unroll
    for (int k2 = 0; k2 < KSPLIT; ++k2)
        s += partial[((size_t)k2 * NPTS + n) * COUT + co];
    float c = cnt[n];
    if (c > 0.f) s /= fmaxf(c, 1.f);
    out[idx] = fmaxf(s + bias[co], 0.f);
}

// ---------------------------------------------------------------------------
// Kernel 5: fused FC chain. One wave per point, __shfl broadcasts.
// ---------------------------------------------------------------------------
__global__ __launch_bounds__(64) void fc_kernel(
    const float* __restrict__ x,
    const float* __restrict__ W1, const float* __restrict__ b1,
    const float* __restrict__ W2, const float* __restrict__ b2,
    const float* __restrict__ W3, const float* __restrict__ b3,
    const float* __restrict__ W4, const float* __restrict__ b4,
    float* __restrict__ out) {
    int n = blockIdx.x;
    int lane = threadIdx.x;
    float xv = (lane < 32) ? x[(size_t)n * 32 + lane] : 0.0f;

    float t = b1[lane];
    for (int ci = 0; ci < 32; ++ci)
        t = fmaf(__shfl(xv, ci), W1[ci * 64 + lane], t);
    float h1 = fmaxf(t, 0.0f);

    t = b2[lane];
    for (int ci = 0; ci < 64; ++ci)
        t = fmaf(__shfl(h1, ci), W2[ci * 64 + lane], t);
    float h2 = fmaxf(t, 0.0f);

    int l32 = lane & 31;
    t = b3[l32];
    for (int ci = 0; ci < 64; ++ci)
        t = fmaf(__shfl(h2, ci), W3[ci * 32 + l32], t);
    float h3 = fmaxf(t, 0.0f);

    int ch = (lane < 3) ? lane : 0;
    float o = b4[ch];
    for (int ci = 0; ci < 32; ++ci)
        o = fmaf(__shfl(h3, ci), W4[ci * 3 + ch], o);
    if (lane < 3) out[(size_t)n * 3 + lane] = o;
}

// ---------------------------------------------------------------------------
// launch
// ---------------------------------------------------------------------------
extern "C" void kernel_launch(void* const* d_in, const int* in_sizes, int n_in,
                              void* d_out, int out_size, void* d_ws, size_t ws_size,
                              hipStream_t stream) {
    const float* feats = (const float*)d_in[0];
    const float* pos   = (const float*)d_in[1];
    const int*   nidx  = (const int*)d_in[2];
    // d_in[3] (neighbor_mask) unused: mask recomputed exactly.
    const float* W1 = (const float*)d_in[4];
    const float* b1 = (const float*)d_in[5];
    const float* W2 = (const float*)d_in[6];
    const float* b2 = (const float*)d_in[7];
    const float* W3 = (const float*)d_in[8];
    const float* b3 = (const float*)d_in[9];
    const float* Wfc1 = (const float*)d_in[10];
    const float* bfc1 = (const float*)d_in[11];
    const float* Wfc2 = (const float*)d_in[12];
    const float* bfc2 = (const float*)d_in[13];
    const float* Wfc3 = (const float*)d_in[14];
    const float* bfc3 = (const float*)d_in[15];
    const float* Wout = (const float*)d_in[16];
    const float* bout = (const float*)d_in[17];

    char* ws = (char*)d_ws;
    uint2* contrib = (uint2*)(ws);                    // 20,578,304 B
    int*   starts  = (int*)  (ws + 20578304);         //    136,276 B
    float* cnt     = (float*)(ws + 20714624);         //     40,000 B
    float* x1      = (float*)(ws + 20754624);         //  2,560,000 B
    float* x2      = (float*)(ws + 23314624);         //  2,560,000 B
    float* x3      = (float*)(ws + 25874624);         //  1,280,000 B
    // geo (5.12 MB) dead after sort -> alias with partial region
    uint4* geo     = (uint4*)(ws + 27154624);
    float* partial = (float*)(ws + 27154624);

    // big: conv2 KSPLIT=8 needs 8 * 2.56 MB = 20.48 MB partial region
    const bool big = ws_size >= (size_t)47634624;

    hipMemsetAsync(cnt, 0, NPTS * sizeof(float), stream);
    geom_kernel<<<(NPTS * KNB) / 256, 256, 0, stream>>>(pos, nidx, geo, cnt);
    sort_kernel<<<NSGT, 256, 0, stream>>>(geo, contrib, starts);

    // conv1: CIN=4, COUT=64, CPC=8 (KC=32), KSPLIT=4 -> partial 10.24 MB
    conv_kernel<4, 64, 8, 4><<<dim3(79, 4), 256, 0, stream>>>(
        feats, W1, contrib, starts, partial);
    combine_kernel<64, 4><<<(NPTS * 64 + 255) / 256, 256, 0, stream>>>(
        partial, cnt, b1, x1);

    // conv2: CIN=64, COUT=64, CPC=1 (KC=64)
    if (big) {
        conv_kernel<64, 64, 1, 8><<<dim3(79, 8), 256, 0, stream>>>(
            x1, W2, contrib, starts, partial);
        combine_kernel<64, 8><<<(NPTS * 64 + 255) / 256, 256, 0, stream>>>(
            partial, cnt, b2, x2);
    } else {
        conv_kernel<64, 64, 1, 4><<<dim3(79, 4), 256, 0, stream>>>(
            x1, W2, contrib, starts, partial);
        combine_kernel<64, 4><<<(NPTS * 64 + 255) / 256, 256, 0, stream>>>(
            partial, cnt, b2, x2);
    }

    // conv3: CIN=64, COUT=32, CPC=1, KSPLIT=8 -> partial 10.24 MB
    conv_kernel<64, 32, 1, 8><<<dim3(79, 8), 256, 0, stream>>>(
        x2, W3, contrib, starts, partial);
    combine_kernel<32, 8><<<(NPTS * 32 + 255) / 256, 256, 0, stream>>>(
        partial, cnt, b3, x3);

    fc_kernel<<<NPTS, 64, 0, stream>>>(x3, Wfc1, bfc1, Wfc2, bfc2,
                                       Wfc3, bfc3, Wout, bout, (float*)d_out);
}

// Round 6
// 2356.609 us; speedup vs baseline: 1.0597x; 1.0597x over previous
//
#include <hip/hip_runtime.h>
#include <math.h>

#define NPTS  10000
#define KNB   32
#define NCELL 216     // 6*6*6
#define NSGT  157     // ceil(NPTS/64) sort groups

// ---------------------------------------------------------------------------
// helpers
// ---------------------------------------------------------------------------
__device__ __forceinline__ float sgnf(float v) {
    return (v > 0.0f) ? 1.0f : ((v < 0.0f) ? -1.0f : 0.0f);
}

// Open3D ball->cube volume-preserving map, transcribed from the reference.
__device__ __forceinline__ void ball_to_cube(float x, float y, float z,
                                             float& X, float& Y, float& Z) {
    const float EPSF = 1e-12f;
    const float FOPI = (float)(4.0 / 3.14159265358979323846);
    float sq   = x * x + y * y + z * z;
    float norm = sqrtf(fmaxf(sq, EPSF));
    float rho2 = x * x + y * y;
    bool in_cone = (1.25f * z * z > rho2);
    float s1 = sqrtf(3.0f * norm / (norm + fabsf(z)));
    float s2 = norm / sqrtf(fmaxf(rho2, EPSF));
    float s  = in_cone ? s1 : s2;
    float xc = x * s;
    float yc = y * s;
    float zc = in_cone ? sgnf(z) * norm : 1.5f * z;
    if (sq < EPSF) { xc = 0.0f; yc = 0.0f; zc = 0.0f; }
    float sq_xy   = xc * xc + yc * yc;
    float norm_xy = sqrtf(fmaxf(sq_xy, EPSF));
    bool x_major = (fabsf(yc) <= fabsf(xc));
    float xd = (fabsf(xc) < EPSF) ? 1.0f : xc;
    float yd = (fabsf(yc) < EPSF) ? 1.0f : yc;
    float tx = sgnf(xc) * norm_xy;
    float ty = sgnf(yc) * norm_xy;
    float xq = x_major ? tx : ty * FOPI * atanf(xc / yd);
    float yq = x_major ? tx * FOPI * atanf(yc / xd) : ty;
    if (sq_xy < EPSF) { xq = 0.0f; yq = 0.0f; }
    X = xq; Y = yq; Z = zc;
}

// ---------------------------------------------------------------------------
// Kernel 1: per-(point,neighbor) geometry record + neighbor counts.
// Record (uint4): x,y,z = trilinear fracs (fp32 bits); w = packed:
//   [7:0]=c000 cell, [8]=dx?, [9]=dy?, [10]=dz?, [11]=valid, [25:12]=nidx
// ---------------------------------------------------------------------------
__global__ __launch_bounds__(256) void geom_kernel(
    const float* __restrict__ pos, const int* __restrict__ nidx,
    uint4* __restrict__ geo, float* __restrict__ cnt) {
    int t = blockIdx.x * 256 + threadIdx.x;
    if (t >= NPTS * KNB) return;
    int j = t >> 5;
    int k = t & 31;
    int nid = nidx[t];
    float px = pos[j * 3], py = pos[j * 3 + 1], pz = pos[j * 3 + 2];
    float qx = pos[nid * 3], qy = pos[nid * 3 + 1], qz = pos[nid * 3 + 2];
    // exact fp32 (no FMA contraction) to reproduce numpy's mask bit-for-bit
    float dx = __fsub_rn(px, qx), dy = __fsub_rn(py, qy), dz = __fsub_rn(pz, qz);
    float d2 = __fadd_rn(__fadd_rn(__fmul_rn(dx, dx), __fmul_rn(dy, dy)),
                         __fmul_rn(dz, dz));
    bool valid = (d2 <= 2.25f);
    if (valid && nid == 0) {
        for (int kk = 0; kk < k; ++kk) {
            if (nidx[j * KNB + kk] == 0) { valid = false; break; }
        }
    }
    uint4 g = make_uint4(0u, 0u, 0u, 0u);
    if (valid) {
        const float C = (float)(2.0 / 3.0);   // 2/EXTENT
        float ux = (qx - px) * C, uy = (qy - py) * C, uz = (qz - pz) * C;
        float X, Y, Z;
        ball_to_cube(ux, uy, uz, X, Y, Z);
        float cs[3] = { (X + 1.0f) * 2.5f, (Y + 1.0f) * 2.5f, (Z + 1.0f) * 2.5f };
        int i0[3], i1[3];
        float fr[3];
        #pragma unroll
        for (int d = 0; d < 3; ++d) {
            float f0 = floorf(cs[d]);
            fr[d] = cs[d] - f0;               // frac from UNCLIPPED floor (ref)
            int a = (int)f0;
            a = min(max(a, 0), 5);
            i0[d] = a;
            i1[d] = min(a + 1, 5);
        }
        int c000 = (i0[0] * 6 + i0[1]) * 6 + i0[2];
        unsigned bits = (unsigned)c000
                      | ((unsigned)(i1[0] - i0[0]) << 8)
                      | ((unsigned)(i1[1] - i0[1]) << 9)
                      | ((unsigned)(i1[2] - i0[2]) << 10)
                      | (1u << 11)
                      | ((unsigned)nid << 12);
        g.x = __float_as_uint(fr[0]);
        g.y = __float_as_uint(fr[1]);
        g.z = __float_as_uint(fr[2]);
        g.w = bits;
        atomicAdd(&cnt[j], 1.0f);
    }
    geo[t] = g;
}

// ---------------------------------------------------------------------------
// Kernel 2: counting sort of corner contributions by CELL per 64-pt sort
// group. Payload packs nid | ptl<<14 | cell<<20. starts[sg][217] = per-cell
// prefix. Built once, consumed by all 3 conv layers.
// ---------------------------------------------------------------------------
__global__ __launch_bounds__(256) void sort_kernel(
    const uint4* __restrict__ geo, uint2* __restrict__ contribs,
    int* __restrict__ starts) {
    __shared__ int hist[NCELL];
    __shared__ int pref[NCELL + 1];
    const int sg = blockIdx.x, tid = threadIdx.x;
    if (tid < NCELL) hist[tid] = 0;
    __syncthreads();
    const int npts = min(64, NPTS - sg * 64);
    const int nrec = npts * KNB;
    const uint4* gb = geo + (size_t)sg * 64 * KNB;
    for (int r = tid; r < nrec; r += 256) {
        uint4 g = gb[r];
        if (g.w & 2048u) {
            int c000 = g.w & 255u;
            int dxo = (g.w & 256u)  ? 36 : 0;
            int dyo = (g.w & 512u)  ? 6  : 0;
            int dzo = (g.w & 1024u) ? 1  : 0;
            #pragma unroll
            for (int c = 0; c < 8; ++c) {
                int cell = c000 + ((c & 4) ? dxo : 0) + ((c & 2) ? dyo : 0)
                                + ((c & 1) ? dzo : 0);
                atomicAdd(&hist[cell], 1);
            }
        }
    }
    __syncthreads();
    if (tid == 0) {
        int run = 0;
        for (int m = 0; m < NCELL; ++m) { pref[m] = run; run += hist[m]; }
        pref[NCELL] = run;
    }
    __syncthreads();
    for (int i = tid; i < NCELL + 1; i += 256)
        starts[sg * (NCELL + 1) + i] = pref[i];
    if (tid < NCELL) hist[tid] = pref[tid];   // cursors
    __syncthreads();
    uint2* cb = contribs + (size_t)sg * 16384;
    for (int r = tid; r < nrec; r += 256) {
        uint4 g = gb[r];
        if (g.w & 2048u) {
            int ptl = r >> 5;
            float fx = __uint_as_float(g.x);
            float fy = __uint_as_float(g.y);
            float fz = __uint_as_float(g.z);
            int c000 = g.w & 255u;
            int dxo = (g.w & 256u)  ? 36 : 0;
            int dyo = (g.w & 512u)  ? 6  : 0;
            int dzo = (g.w & 1024u) ? 1  : 0;
            int nid = (g.w >> 12) & 16383u;
            #pragma unroll
            for (int c = 0; c < 8; ++c) {
                float wgt = ((c & 4) ? fx : 1.f - fx)
                          * ((c & 2) ? fy : 1.f - fy)
                          * ((c & 1) ? fz : 1.f - fz);
                int cell = c000 + ((c & 4) ? dxo : 0) + ((c & 2) ? dyo : 0)
                                + ((c & 1) ? dzo : 0);
                int p = atomicAdd(&hist[cell], 1);
                cb[p] = make_uint2(__float_as_uint(wgt),
                                   (unsigned)nid | ((unsigned)ptl << 14)
                                                 | ((unsigned)cell << 20));
            }
        }
    }
}

// ---------------------------------------------------------------------------
// Kernel 3: conv, SINGLE-WAVE workgroups (64 threads). Each 1-wave block owns
// PTILE=NSG*64 points and all COUT outputs; per chunk the wave sequentially
// does: zero A-tile -> lane-parallel scatter (U=4 batched gather + ds_add)
// -> 8pt x 8co register-tile GEMM (A from LDS b128, W from global b128 --
// 16 KB W chunk is L1-resident and shared by all co-resident blocks).
// No multi-wave barriers anywhere; latency hiding comes from ~8 independent
// 1-wave blocks per CU (A-only LDS is small). K-split over blockIdx.y.
// ---------------------------------------------------------------------------
template<int CIN, int COUT, int CPC, int NSG, int KSPLIT>
__global__ __launch_bounds__(64, 1) void conv_kernel(
    const float* __restrict__ feats, const float* __restrict__ W,
    const uint2* __restrict__ contribs, const int* __restrict__ starts,
    float* __restrict__ partial) {
    constexpr int KC    = CPC * CIN;      // K per chunk (32 or 64)
    constexpr int AQ    = KC / 4 + 1;     // A row stride in float4s (odd)
    constexpr int PTILE = NSG * 64;
    constexpr int CTH   = COUT / 8;       // co-threads (8 or 4)
    constexpr int PTH   = 64 / CTH;       // pt-threads (8 or 16)
    static_assert(PTH * 8 == PTILE, "tile mismatch");
    constexpr int NCHUNK = NCELL / CPC;
    constexpr int TPC   = CIN / 4;        // threads per contribution
    constexpr int NSLOT = 64 / TPC;
    constexpr int U     = 4;

    __shared__ float4 A4[PTILE * AQ];
    __shared__ int Sl[NSG][NCELL + 1];

    const int lane = threadIdx.x;
    const int cog  = lane % CTH;
    const int ptg  = lane / CTH;
    const int bx   = blockIdx.x;
    const int ks   = blockIdx.y;
    const int slot = lane / TPC;
    const int ch   = lane % TPC;
    float* A = reinterpret_cast<float*>(A4);

    for (int s2 = 0; s2 < NSG; ++s2) {
        int sg = bx * NSG + s2;
        for (int i = lane; i < NCELL + 1; i += 64)
            Sl[s2][i] = (sg < NSGT) ? starts[sg * (NCELL + 1) + i] : 0;
    }

    const int c0 = NCHUNK * ks / KSPLIT;
    const int c1 = NCHUNK * (ks + 1) / KSPLIT;

    float4 acc[8][2];
    #pragma unroll
    for (int p = 0; p < 8; ++p) {
        acc[p][0] = make_float4(0.f, 0.f, 0.f, 0.f);
        acc[p][1] = make_float4(0.f, 0.f, 0.f, 0.f);
    }

    for (int c = c0; c < c1; ++c) {
        // --- zero A tile (17 float4 stores per lane) ---
        {
            float4 z = make_float4(0.f, 0.f, 0.f, 0.f);
            #pragma unroll
            for (int i = 0; i < PTILE * AQ / 64; ++i) A4[i * 64 + lane] = z;
        }
        __syncthreads();   // single wave: s_waitcnt + cheap barrier
        // --- scatter this chunk's contributions ---
        const int cb = c * CPC;
        #pragma unroll
        for (int s2 = 0; s2 < NSG; ++s2) {
            const uint2* cbs = contribs + (size_t)(bx * NSG + s2) * 16384;
            const int s = Sl[s2][cb], e = Sl[s2][cb + CPC];
            for (int i = s + slot; i < e; i += U * NSLOT) {
                uint2 recs[U];
                #pragma unroll
                for (int u = 0; u < U; ++u)
                    recs[u] = cbs[min(i + u * NSLOT, e - 1)];   // batch-issue
                float4 f4[U];
                #pragma unroll
                for (int u = 0; u < U; ++u)
                    f4[u] = *reinterpret_cast<const float4*>(
                        feats + (size_t)(recs[u].y & 16383) * CIN + ch * 4);
                #pragma unroll
                for (int u = 0; u < U; ++u) {
                    int idx = i + u * NSLOT;
                    if (idx < e) {
                        float wgt = __uint_as_float(recs[u].x);
                        int ptl = (recs[u].y >> 14) & 63;
                        int cel = (int)(recs[u].y >> 20);
                        float* dst = A + (size_t)(s2 * 64 + ptl) * (AQ * 4)
                                   + (cel - cb) * CIN + ch * 4;
                        atomicAdd(dst + 0, wgt * f4[u].x);
                        atomicAdd(dst + 1, wgt * f4[u].y);
                        atomicAdd(dst + 2, wgt * f4[u].z);
                        atomicAdd(dst + 3, wgt * f4[u].w);
                    }
                }
            }
        }
        __syncthreads();
        // --- 8pt x 8co GEMM: A LDS b128 (per-lane-distinct), W global b128 ---
        const float* Wc = W + (size_t)c * KC * COUT;
        #pragma unroll 2
        for (int g = 0; g < KC / 4; ++g) {
            float4 wv[4][2];
            #pragma unroll
            for (int j = 0; j < 4; ++j) {
                const float* wp = Wc + (size_t)(g * 4 + j) * COUT + cog * 8;
                wv[j][0] = *reinterpret_cast<const float4*>(wp);
                wv[j][1] = *reinterpret_cast<const float4*>(wp + 4);
            }
            float4 av[8];
            #pragma unroll
            for (int p = 0; p < 8; ++p)
                av[p] = A4[(ptg * 8 + p) * AQ + g];
            #pragma unroll
            for (int p = 0; p < 8; ++p) {
                const float* ap = reinterpret_cast<const float*>(&av[p]);
                #pragma unroll
                for (int j = 0; j < 4; ++j) {
                    float a = ap[j];
                    acc[p][0].x = fmaf(a, wv[j][0].x, acc[p][0].x);
                    acc[p][0].y = fmaf(a, wv[j][0].y, acc[p][0].y);
                    acc[p][0].z = fmaf(a, wv[j][0].z, acc[p][0].z);
                    acc[p][0].w = fmaf(a, wv[j][0].w, acc[p][0].w);
                    acc[p][1].x = fmaf(a, wv[j][1].x, acc[p][1].x);
                    acc[p][1].y = fmaf(a, wv[j][1].y, acc[p][1].y);
                    acc[p][1].z = fmaf(a, wv[j][1].z, acc[p][1].z);
                    acc[p][1].w = fmaf(a, wv[j][1].w, acc[p][1].w);
                }
            }
        }
        __syncthreads();
    }

    #pragma unroll
    for (int p = 0; p < 8; ++p) {
        int n = bx * PTILE + ptg * 8 + p;
        if (n < NPTS) {
            float* po = partial + ((size_t)ks * NPTS + n) * COUT + cog * 8;
            *reinterpret_cast<float4*>(po)     = acc[p][0];
            *reinterpret_cast<float4*>(po + 4) = acc[p][1];
        }
    }
}

// ---------------------------------------------------------------------------
// Kernel 4: combine K-split partials, normalize by neighbor count, bias, relu.
// ---------------------------------------------------------------------------
template<int COUT, int KSPLIT>
__global__ __launch_bounds__(256) void combine_kernel(
    const float* __restrict__ partial, const float* __restrict__ cnt,
    const float* __restrict__ bias, float* __restrict__ out) {
    int idx = blockIdx.x * 256 + threadIdx.x;
    if (idx >= NPTS * COUT) return;
    int n = idx / COUT, co = idx % COUT;
    float s = 0.f;
    #pragma unroll
    for (int k2 = 0; k2 < KSPLIT; ++k2)
        s += partial[((size_t)k2 * NPTS + n) * COUT + co];
    float c = cnt[n];
    if (c > 0.f) s /= fmaxf(c, 1.f);
    out[idx] = fmaxf(s + bias[co], 0.f);
}

// ---------------------------------------------------------------------------
// Kernel 5: fused FC chain. One wave per point, __shfl broadcasts.
// ---------------------------------------------------------------------------
__global__ __launch_bounds__(64) void fc_kernel(
    const float* __restrict__ x,
    const float* __restrict__ W1, const float* __restrict__ b1,
    const float* __restrict__ W2, const float* __restrict__ b2,
    const float* __restrict__ W3, const float* __restrict__ b3,
    const float* __restrict__ W4, const float* __restrict__ b4,
    float* __restrict__ out) {
    int n = blockIdx.x;
    int lane = threadIdx.x;
    float xv = (lane < 32) ? x[(size_t)n * 32 + lane] : 0.0f;

    float t = b1[lane];
    for (int ci = 0; ci < 32; ++ci)
        t = fmaf(__shfl(xv, ci), W1[ci * 64 + lane], t);
    float h1 = fmaxf(t, 0.0f);

    t = b2[lane];
    for (int ci = 0; ci < 64; ++ci)
        t = fmaf(__shfl(h1, ci), W2[ci * 64 + lane], t);
    float h2 = fmaxf(t, 0.0f);

    int l32 = lane & 31;
    t = b3[l32];
    for (int ci = 0; ci < 64; ++ci)
        t = fmaf(__shfl(h2, ci), W3[ci * 32 + l32], t);
    float h3 = fmaxf(t, 0.0f);

    int ch = (lane < 3) ? lane : 0;
    float o = b4[ch];
    for (int ci = 0; ci < 32; ++ci)
        o = fmaf(__shfl(h3, ci), W4[ci * 3 + ch], o);
    if (lane < 3) out[(size_t)n * 3 + lane] = o;
}

// ---------------------------------------------------------------------------
// launch
// ---------------------------------------------------------------------------
extern "C" void kernel_launch(void* const* d_in, const int* in_sizes, int n_in,
                              void* d_out, int out_size, void* d_ws, size_t ws_size,
                              hipStream_t stream) {
    const float* feats = (const float*)d_in[0];
    const float* pos   = (const float*)d_in[1];
    const int*   nidx  = (const int*)d_in[2];
    // d_in[3] (neighbor_mask) unused: mask recomputed exactly.
    const float* W1 = (const float*)d_in[4];
    const float* b1 = (const float*)d_in[5];
    const float* W2 = (const float*)d_in[6];
    const float* b2 = (const float*)d_in[7];
    const float* W3 = (const float*)d_in[8];
    const float* b3 = (const float*)d_in[9];
    const float* Wfc1 = (const float*)d_in[10];
    const float* bfc1 = (const float*)d_in[11];
    const float* Wfc2 = (const float*)d_in[12];
    const float* bfc2 = (const float*)d_in[13];
    const float* Wfc3 = (const float*)d_in[14];
    const float* bfc3 = (const float*)d_in[15];
    const float* Wout = (const float*)d_in[16];
    const float* bout = (const float*)d_in[17];

    char* ws = (char*)d_ws;
    uint2* contrib = (uint2*)(ws);                    // 20,578,304 B
    int*   starts  = (int*)  (ws + 20578304);         //    136,276 B
    float* cnt     = (float*)(ws + 20714624);         //     40,000 B
    float* x1      = (float*)(ws + 20754624);         //  2,560,000 B
    float* x2      = (float*)(ws + 23314624);         //  2,560,000 B
    float* x3      = (float*)(ws + 25874624);         //  1,280,000 B
    // geo (5.12 MB) dead after sort -> alias with partial region
    uint4* geo     = (uint4*)(ws + 27154624);
    float* partial = (float*)(ws + 27154624);

    // big: conv2 KSPLIT=8 needs 8 * 2.56 MB = 20.48 MB partial region
    const bool big = ws_size >= (size_t)47634624;

    hipMemsetAsync(cnt, 0, NPTS * sizeof(float), stream);
    geom_kernel<<<(NPTS * KNB) / 256, 256, 0, stream>>>(pos, nidx, geo, cnt);
    sort_kernel<<<NSGT, 256, 0, stream>>>(geo, contrib, starts);

    // conv1: CIN=4, COUT=64, CPC=8 (KC=32), 1 sg/block, KSPLIT=3
    conv_kernel<4, 64, 8, 1, 3><<<dim3(NSGT, 3), 64, 0, stream>>>(
        feats, W1, contrib, starts, partial);
    combine_kernel<64, 3><<<(NPTS * 64 + 255) / 256, 256, 0, stream>>>(
        partial, cnt, b1, x1);

    // conv2: CIN=64, COUT=64, CPC=1 (KC=64), 1 sg/block
    if (big) {
        conv_kernel<64, 64, 1, 1, 8><<<dim3(NSGT, 8), 64, 0, stream>>>(
            x1, W2, contrib, starts, partial);
        combine_kernel<64, 8><<<(NPTS * 64 + 255) / 256, 256, 0, stream>>>(
            partial, cnt, b2, x2);
    } else {
        conv_kernel<64, 64, 1, 1, 4><<<dim3(NSGT, 4), 64, 0, stream>>>(
            x1, W2, contrib, starts, partial);
        combine_kernel<64, 4><<<(NPTS * 64 + 255) / 256, 256, 0, stream>>>(
            partial, cnt, b2, x2);
    }

    // conv3: CIN=64, COUT=32, CPC=1, 2 sgs/block (128 pts), KSPLIT=8
    conv_kernel<64, 32, 1, 2, 8><<<dim3(79, 8), 64, 0, stream>>>(
        x2, W3, contrib, starts, partial);
    combine_kernel<32, 8><<<(NPTS * 32 + 255) / 256, 256, 0, stream>>>(
        partial, cnt, b3, x3);

    fc_kernel<<<NPTS, 64, 0, stream>>>(x3, Wfc1, bfc1, Wfc2, bfc2,
                                       Wfc3, bfc3, Wout, bout, (float*)d_out);
}

// Round 8
// 2251.359 us; speedup vs baseline: 1.1092x; 1.0467x over previous
//
#include <hip/hip_runtime.h>
#include <math.h>

#define NPTS  10000
#define KNB   32
#define NCELL 216     // 6*6*6
#define NSGT  157     // ceil(NPTS/64) sort groups

// ---------------------------------------------------------------------------
// helpers
// ---------------------------------------------------------------------------
__device__ __forceinline__ float sgnf(float v) {
    return (v > 0.0f) ? 1.0f : ((v < 0.0f) ? -1.0f : 0.0f);
}

__device__ __forceinline__ int ld_acq(int* p) {
    return __hip_atomic_load(p, __ATOMIC_ACQUIRE, __HIP_MEMORY_SCOPE_WORKGROUP);
}
__device__ __forceinline__ void add_rel(int* p) {
    __hip_atomic_fetch_add(p, 1, __ATOMIC_RELEASE, __HIP_MEMORY_SCOPE_WORKGROUP);
}

// Open3D ball->cube volume-preserving map, transcribed from the reference.
__device__ __forceinline__ void ball_to_cube(float x, float y, float z,
                                             float& X, float& Y, float& Z) {
    const float EPSF = 1e-12f;
    const float FOPI = (float)(4.0 / 3.14159265358979323846);
    float sq   = x * x + y * y + z * z;
    float norm = sqrtf(fmaxf(sq, EPSF));
    float rho2 = x * x + y * y;
    bool in_cone = (1.25f * z * z > rho2);
    float s1 = sqrtf(3.0f * norm / (norm + fabsf(z)));
    float s2 = norm / sqrtf(fmaxf(rho2, EPSF));
    float s  = in_cone ? s1 : s2;
    float xc = x * s;
    float yc = y * s;
    float zc = in_cone ? sgnf(z) * norm : 1.5f * z;
    if (sq < EPSF) { xc = 0.0f; yc = 0.0f; zc = 0.0f; }
    float sq_xy   = xc * xc + yc * yc;
    float norm_xy = sqrtf(fmaxf(sq_xy, EPSF));
    bool x_major = (fabsf(yc) <= fabsf(xc));
    float xd = (fabsf(xc) < EPSF) ? 1.0f : xc;
    float yd = (fabsf(yc) < EPSF) ? 1.0f : yc;
    float tx = sgnf(xc) * norm_xy;
    float ty = sgnf(yc) * norm_xy;
    float xq = x_major ? tx : ty * FOPI * atanf(xc / yd);
    float yq = x_major ? tx * FOPI * atanf(yc / xd) : ty;
    if (sq_xy < EPSF) { xq = 0.0f; yq = 0.0f; }
    X = xq; Y = yq; Z = zc;
}

// ---------------------------------------------------------------------------
// Kernel 1: per-(point,neighbor) geometry record + neighbor counts.
// Record (uint4): x,y,z = trilinear fracs (fp32 bits); w = packed:
//   [7:0]=c000 cell, [8]=dx?, [9]=dy?, [10]=dz?, [11]=valid, [25:12]=nidx
// ---------------------------------------------------------------------------
__global__ __launch_bounds__(256) void geom_kernel(
    const float* __restrict__ pos, const int* __restrict__ nidx,
    uint4* __restrict__ geo, float* __restrict__ cnt) {
    int t = blockIdx.x * 256 + threadIdx.x;
    if (t >= NPTS * KNB) return;
    int j = t >> 5;
    int k = t & 31;
    int nid = nidx[t];
    float px = pos[j * 3], py = pos[j * 3 + 1], pz = pos[j * 3 + 2];
    float qx = pos[nid * 3], qy = pos[nid * 3 + 1], qz = pos[nid * 3 + 2];
    // exact fp32 (no FMA contraction) to reproduce numpy's mask bit-for-bit
    float dx = __fsub_rn(px, qx), dy = __fsub_rn(py, qy), dz = __fsub_rn(pz, qz);
    float d2 = __fadd_rn(__fadd_rn(__fmul_rn(dx, dx), __fmul_rn(dy, dy)),
                         __fmul_rn(dz, dz));
    bool valid = (d2 <= 2.25f);
    if (valid && nid == 0) {
        for (int kk = 0; kk < k; ++kk) {
            if (nidx[j * KNB + kk] == 0) { valid = false; break; }
        }
    }
    uint4 g = make_uint4(0u, 0u, 0u, 0u);
    if (valid) {
        const float C = (float)(2.0 / 3.0);   // 2/EXTENT
        float ux = (qx - px) * C, uy = (qy - py) * C, uz = (qz - pz) * C;
        float X, Y, Z;
        ball_to_cube(ux, uy, uz, X, Y, Z);
        float cs[3] = { (X + 1.0f) * 2.5f, (Y + 1.0f) * 2.5f, (Z + 1.0f) * 2.5f };
        int i0[3], i1[3];
        float fr[3];
        #pragma unroll
        for (int d = 0; d < 3; ++d) {
            float f0 = floorf(cs[d]);
            fr[d] = cs[d] - f0;               // frac from UNCLIPPED floor (ref)
            int a = (int)f0;
            a = min(max(a, 0), 5);
            i0[d] = a;
            i1[d] = min(a + 1, 5);
        }
        int c000 = (i0[0] * 6 + i0[1]) * 6 + i0[2];
        unsigned bits = (unsigned)c000
                      | ((unsigned)(i1[0] - i0[0]) << 8)
                      | ((unsigned)(i1[1] - i0[1]) << 9)
                      | ((unsigned)(i1[2] - i0[2]) << 10)
                      | (1u << 11)
                      | ((unsigned)nid << 12);
        g.x = __float_as_uint(fr[0]);
        g.y = __float_as_uint(fr[1]);
        g.z = __float_as_uint(fr[2]);
        g.w = bits;
        atomicAdd(&cnt[j], 1.0f);
    }
    geo[t] = g;
}

// ---------------------------------------------------------------------------
// Kernel 2: counting sort of corner contributions by CELL per 64-pt sort
// group. Payload packs nid | ptl<<14 | cell<<20. starts[sg][217] = per-cell
// prefix. Built once, consumed by all 3 conv layers.
// ---------------------------------------------------------------------------
__global__ __launch_bounds__(256) void sort_kernel(
    const uint4* __restrict__ geo, uint2* __restrict__ contribs,
    int* __restrict__ starts) {
    __shared__ int hist[NCELL];
    __shared__ int pref[NCELL + 1];
    const int sg = blockIdx.x, tid = threadIdx.x;
    if (tid < NCELL) hist[tid] = 0;
    __syncthreads();
    const int npts = min(64, NPTS - sg * 64);
    const int nrec = npts * KNB;
    const uint4* gb = geo + (size_t)sg * 64 * KNB;
    for (int r = tid; r < nrec; r += 256) {
        uint4 g = gb[r];
        if (g.w & 2048u) {
            int c000 = g.w & 255u;
            int dxo = (g.w & 256u)  ? 36 : 0;
            int dyo = (g.w & 512u)  ? 6  : 0;
            int dzo = (g.w & 1024u) ? 1  : 0;
            #pragma unroll
            for (int c = 0; c < 8; ++c) {
                int cell = c000 + ((c & 4) ? dxo : 0) + ((c & 2) ? dyo : 0)
                                + ((c & 1) ? dzo : 0);
                atomicAdd(&hist[cell], 1);
            }
        }
    }
    __syncthreads();
    if (tid == 0) {
        int run = 0;
        for (int m = 0; m < NCELL; ++m) { pref[m] = run; run += hist[m]; }
        pref[NCELL] = run;
    }
    __syncthreads();
    for (int i = tid; i < NCELL + 1; i += 256)
        starts[sg * (NCELL + 1) + i] = pref[i];
    if (tid < NCELL) hist[tid] = pref[tid];   // cursors
    __syncthreads();
    uint2* cb = contribs + (size_t)sg * 16384;
    for (int r = tid; r < nrec; r += 256) {
        uint4 g = gb[r];
        if (g.w & 2048u) {
            int ptl = r >> 5;
            float fx = __uint_as_float(g.x);
            float fy = __uint_as_float(g.y);
            float fz = __uint_as_float(g.z);
            int c000 = g.w & 255u;
            int dxo = (g.w & 256u)  ? 36 : 0;
            int dyo = (g.w & 512u)  ? 6  : 0;
            int dzo = (g.w & 1024u) ? 1  : 0;
            int nid = (g.w >> 12) & 16383u;
            #pragma unroll
            for (int c = 0; c < 8; ++c) {
                float wgt = ((c & 4) ? fx : 1.f - fx)
                          * ((c & 2) ? fy : 1.f - fy)
                          * ((c & 1) ? fz : 1.f - fz);
                int cell = c000 + ((c & 4) ? dxo : 0) + ((c & 2) ? dyo : 0)
                                + ((c & 1) ? dzo : 0);
                int p = atomicAdd(&hist[cell], 1);
                cb[p] = make_uint2(__float_as_uint(wgt),
                                   (unsigned)nid | ((unsigned)ptl << 14)
                                                 | ((unsigned)cell << 20));
            }
        }
    }
}

// ---------------------------------------------------------------------------
// Kernel 3: conv with PRODUCER/CONSUMER WAVE SPECIALIZATION (fixed sync).
// Block = 256 thr = 4 waves, one 64-pt sort group. Roles rotated by bx so
// consumer waves spread across SIMDs. 2 producer waves fill a depth-2 LDS
// ring (zero + batched gather + ds_add scatter); 2 consumer waves run a
// 4pt x CO_T register-tile GEMM (A rows interleaved ptg+p*16: conflict-free
// ds_read_b128; W from global, coalesced, L1/L2-resident).
// All cross-wave sync via LDS atomics with acquire/release at workgroup
// scope (compiler cannot reorder Ring accesses across them) -- no barriers
// in the loop. Per-slot counters are monotone -> race-free.
// K-split over blockIdx.y into partial buffers (combined later).
// ---------------------------------------------------------------------------
template<int CIN, int COUT, int CPC, int KSPLIT, int CO_T>
__global__ __launch_bounds__(256, 3) void conv_kernel(
    const float* __restrict__ feats, const float* __restrict__ W,
    const uint2* __restrict__ contribs, const int* __restrict__ starts,
    float* __restrict__ partial) {
    constexpr int KC   = CPC * CIN;       // K per chunk (32 or 64)
    constexpr int AQ   = KC / 4 + 1;      // row stride in float4 (odd)
    constexpr int RD   = 2;               // ring depth
    constexpr int NCHUNK = NCELL / CPC;
    constexpr int NPW  = 2, NCW = 2;      // producer / consumer waves
    constexpr int NCOG = COUT / CO_T;     // 8
    constexpr int TPC  = CIN / 4;         // threads per contribution
    constexpr int NSLOT = 128 / TPC;
    constexpr int U    = 4;
    constexpr int Q4   = CO_T / 4;        // 2 or 1

    __shared__ float4 Ring[RD][64 * AQ];
    __shared__ int Sl[NCELL + 1];
    __shared__ int zeroc[RD], prodc[RD], consc[RD];

    const int tid  = threadIdx.x;
    const int lane = tid & 63;
    const int wave = tid >> 6;
    const int bx   = blockIdx.x;          // sort group
    const int ks   = blockIdx.y;

    // role rotation: spread consumer waves across SIMDs over blocks
    const int rw   = (wave + (bx & 3)) & 3;
    const bool producer = (rw >= 2);
    const int rtid = (rw & 1) * 64 + lane;   // role-local tid 0..127

    for (int i = tid; i < NCELL + 1; i += 256)
        Sl[i] = starts[bx * (NCELL + 1) + i];
    if (tid < RD) { zeroc[tid] = 0; prodc[tid] = 0; consc[tid] = 0; }
    __syncthreads();                      // only block-wide barrier

    const int c0 = NCHUNK * ks / KSPLIT;
    const int c1 = NCHUNK * (ks + 1) / KSPLIT;

    if (producer) {
        // ----------------- PRODUCER -----------------
        const int slot = rtid / TPC;
        const int ch   = rtid % TPC;
        const uint2* cbs = contribs + (size_t)bx * 16384;
        for (int c = c0; c < c1; ++c) {
            const int i = c - c0, s = i % RD, lap = i / RD;
            while (ld_acq(&consc[s]) < NCW * lap) __builtin_amdgcn_s_sleep(2);
            {   // zero own share of the slot
                float4 z = make_float4(0.f, 0.f, 0.f, 0.f);
                float4* dst = &Ring[s][0];
                for (int j = rtid; j < 64 * AQ; j += 128) dst[j] = z;
            }
            if (lane == 0) add_rel(&zeroc[s]);
            while (ld_acq(&zeroc[s]) < NPW * (lap + 1)) __builtin_amdgcn_s_sleep(1);
            // scatter this chunk's contributions
            const int cb = c * CPC;
            const int sbeg = Sl[cb], send = Sl[cb + CPC];
            float* A = (float*)&Ring[s][0];
            for (int it = sbeg + slot; it < send; it += U * NSLOT) {
                uint2 recs[U];
                #pragma unroll
                for (int u = 0; u < U; ++u)
                    recs[u] = cbs[min(it + u * NSLOT, send - 1)];  // batch-issue
                float4 f4[U];
                #pragma unroll
                for (int u = 0; u < U; ++u)
                    f4[u] = *reinterpret_cast<const float4*>(
                        feats + (size_t)(recs[u].y & 16383) * CIN + ch * 4);
                #pragma unroll
                for (int u = 0; u < U; ++u) {
                    int idx = it + u * NSLOT;
                    if (idx < send) {
                        float wgt = __uint_as_float(recs[u].x);
                        int ptl = (recs[u].y >> 14) & 63;
                        int cel = (int)(recs[u].y >> 20);
                        float* dst = A + ptl * (AQ * 4) + (cel - cb) * CIN + ch * 4;
                        atomicAdd(dst + 0, wgt * f4[u].x);
                        atomicAdd(dst + 1, wgt * f4[u].y);
                        atomicAdd(dst + 2, wgt * f4[u].z);
                        atomicAdd(dst + 3, wgt * f4[u].w);
                    }
                }
            }
            if (lane == 0) add_rel(&prodc[s]);
        }
    } else {
        // ----------------- CONSUMER -----------------
        const int cog = rtid % NCOG;      // 0..7
        const int ptg = rtid / NCOG;      // 0..15 (rows ptg + p*16: interleaved)
        float4 acc[4][Q4];
        #pragma unroll
        for (int p = 0; p < 4; ++p)
            #pragma unroll
            for (int q = 0; q < Q4; ++q)
                acc[p][q] = make_float4(0.f, 0.f, 0.f, 0.f);

        for (int c = c0; c < c1; ++c) {
            const int i = c - c0, s = i % RD, lap = i / RD;
            while (ld_acq(&prodc[s]) < NPW * (lap + 1)) __builtin_amdgcn_s_sleep(2);
            const float* Wc = W + (size_t)c * KC * COUT + cog * CO_T;
            const float4* Ar = &Ring[s][0];
            #pragma unroll 2
            for (int g = 0; g < KC / 4; ++g) {
                float4 wv[4][Q4];
                #pragma unroll
                for (int j = 0; j < 4; ++j) {
                    const float* wp = Wc + (size_t)(g * 4 + j) * COUT;
                    #pragma unroll
                    for (int q = 0; q < Q4; ++q)
                        wv[j][q] = *reinterpret_cast<const float4*>(wp + q * 4);
                }
                float4 av[4];
                #pragma unroll
                for (int p = 0; p < 4; ++p)
                    av[p] = Ar[(ptg + p * 16) * AQ + g];   // conflict-free b128
                #pragma unroll
                for (int p = 0; p < 4; ++p) {
                    const float* ap = reinterpret_cast<const float*>(&av[p]);
                    #pragma unroll
                    for (int j = 0; j < 4; ++j) {
                        float a = ap[j];
                        #pragma unroll
                        for (int q = 0; q < Q4; ++q) {
                            acc[p][q].x = fmaf(a, wv[j][q].x, acc[p][q].x);
                            acc[p][q].y = fmaf(a, wv[j][q].y, acc[p][q].y);
                            acc[p][q].z = fmaf(a, wv[j][q].z, acc[p][q].z);
                            acc[p][q].w = fmaf(a, wv[j][q].w, acc[p][q].w);
                        }
                    }
                }
            }
            if (lane == 0) add_rel(&consc[s]);   // release waits our ds_reads
        }

        #pragma unroll
        for (int p = 0; p < 4; ++p) {
            int n = bx * 64 + ptg + p * 16;
            if (n < NPTS) {
                float* po = partial + ((size_t)ks * NPTS + n) * COUT + cog * CO_T;
                #pragma unroll
                for (int q = 0; q < Q4; ++q)
                    *reinterpret_cast<float4*>(po + q * 4) = acc[p][q];
            }
        }
    }
}

// ---------------------------------------------------------------------------
// Kernel 4: combine K-split partials, normalize by neighbor count, bias, relu.
// ---------------------------------------------------------------------------
template<int COUT, int KSPLIT>
__global__ __launch_bounds__(256) void combine_kernel(
    const float* __restrict__ partial, const float* __restrict__ cnt,
    const float* __restrict__ bias, float* __restrict__ out) {
    int idx = blockIdx.x * 256 + threadIdx.x;
    if (idx >= NPTS * COUT) return;
    int n = idx / COUT, co = idx % COUT;
    float s = 0.f;
    #pragma unroll
    for (int k2 = 0; k2 < KSPLIT; ++k2)
        s += partial[((size_t)k2 * NPTS + n) * COUT + co];
    float c = cnt[n];
    if (c > 0.f) s /= fmaxf(c, 1.f);
    out[idx] = fmaxf(s + bias[co], 0.f);
}

// ---------------------------------------------------------------------------
// Kernel 5: fused FC chain. One wave per point, __shfl broadcasts.
// ---------------------------------------------------------------------------
__global__ __launch_bounds__(64) void fc_kernel(
    const float* __restrict__ x,
    const float* __restrict__ W1, const float* __restrict__ b1,
    const float* __restrict__ W2, const float* __restrict__ b2,
    const float* __restrict__ W3, const float* __restrict__ b3,
    const float* __restrict__ W4, const float* __restrict__ b4,
    float* __restrict__ out) {
    int n = blockIdx.x;
    int lane = threadIdx.x;
    float xv = (lane < 32) ? x[(size_t)n * 32 + lane] : 0.0f;

    float t = b1[lane];
    for (int ci = 0; ci < 32; ++ci)
        t = fmaf(__shfl(xv, ci), W1[ci * 64 + lane], t);
    float h1 = fmaxf(t, 0.0f);

    t = b2[lane];
    for (int ci = 0; ci < 64; ++ci)
        t = fmaf(__shfl(h1, ci), W2[ci * 64 + lane], t);
    float h2 = fmaxf(t, 0.0f);

    int l32 = lane & 31;
    t = b3[l32];
    for (int ci = 0; ci < 64; ++ci)
        t = fmaf(__shfl(h2, ci), W3[ci * 32 + l32], t);
    float h3 = fmaxf(t, 0.0f);

    int ch = (lane < 3) ? lane : 0;
    float o = b4[ch];
    for (int ci = 0; ci < 32; ++ci)
        o = fmaf(__shfl(h3, ci), W4[ci * 3 + ch], o);
    if (lane < 3) out[(size_t)n * 3 + lane] = o;
}

// ---------------------------------------------------------------------------
// launch
// ---------------------------------------------------------------------------
extern "C" void kernel_launch(void* const* d_in, const int* in_sizes, int n_in,
                              void* d_out, int out_size, void* d_ws, size_t ws_size,
                              hipStream_t stream) {
    const float* feats = (const float*)d_in[0];
    const float* pos   = (const float*)d_in[1];
    const int*   nidx  = (const int*)d_in[2];
    // d_in[3] (neighbor_mask) unused: mask recomputed exactly.
    const float* W1 = (const float*)d_in[4];
    const float* b1 = (const float*)d_in[5];
    const float* W2 = (const float*)d_in[6];
    const float* b2 = (const float*)d_in[7];
    const float* W3 = (const float*)d_in[8];
    const float* b3 = (const float*)d_in[9];
    const float* Wfc1 = (const float*)d_in[10];
    const float* bfc1 = (const float*)d_in[11];
    const float* Wfc2 = (const float*)d_in[12];
    const float* bfc2 = (const float*)d_in[13];
    const float* Wfc3 = (const float*)d_in[14];
    const float* bfc3 = (const float*)d_in[15];
    const float* Wout = (const float*)d_in[16];
    const float* bout = (const float*)d_in[17];

    char* ws = (char*)d_ws;
    uint2* contrib = (uint2*)(ws);                    // 20,578,304 B
    int*   starts  = (int*)  (ws + 20578304);         //    136,276 B
    float* cnt     = (float*)(ws + 20714624);         //     40,000 B
    float* x1      = (float*)(ws + 20754624);         //  2,560,000 B
    float* x2      = (float*)(ws + 23314624);         //  2,560,000 B
    float* x3      = (float*)(ws + 25874624);         //  1,280,000 B
    // geo (5.12 MB) dead after sort -> alias with partial region
    uint4* geo     = (uint4*)(ws + 27154624);
    float* partial = (float*)(ws + 27154624);         // 10.24 MB max

    hipMemsetAsync(cnt, 0, NPTS * sizeof(float), stream);
    geom_kernel<<<(NPTS * KNB) / 256, 256, 0, stream>>>(pos, nidx, geo, cnt);
    sort_kernel<<<NSGT, 256, 0, stream>>>(geo, contrib, starts);

    // conv1: CIN=4, COUT=64, CPC=8 (KC=32), KSPLIT=3, CO_T=8
    conv_kernel<4, 64, 8, 3, 8><<<dim3(NSGT, 3), 256, 0, stream>>>(
        feats, W1, contrib, starts, partial);
    combine_kernel<64, 3><<<(NPTS * 64 + 255) / 256, 256, 0, stream>>>(
        partial, cnt, b1, x1);

    // conv2: CIN=64, COUT=64, CPC=1 (KC=64), KSPLIT=4, CO_T=8
    conv_kernel<64, 64, 1, 4, 8><<<dim3(NSGT, 4), 256, 0, stream>>>(
        x1, W2, contrib, starts, partial);
    combine_kernel<64, 4><<<(NPTS * 64 + 255) / 256, 256, 0, stream>>>(
        partial, cnt, b2, x2);

    // conv3: CIN=64, COUT=32, CPC=1, KSPLIT=4, CO_T=4
    conv_kernel<64, 32, 1, 4, 4><<<dim3(NSGT, 4), 256, 0, stream>>>(
        x2, W3, contrib, starts, partial);
    combine_kernel<32, 4><<<(NPTS * 32 + 255) / 256, 256, 0, stream>>>(
        partial, cnt, b3, x3);

    fc_kernel<<<NPTS, 64, 0, stream>>>(x3, Wfc1, bfc1, Wfc2, bfc2,
                                       Wfc3, bfc3, Wout, bout, (float*)d_out);
}

// Round 9
// 2200.156 us; speedup vs baseline: 1.1350x; 1.0233x over previous
//
#include <hip/hip_runtime.h>
#include <math.h>

#define NPTS  10000
#define KNB   32
#define NCELL 216     // 6*6*6
#define NSGT  157     // ceil(NPTS/64) sort groups

// ---------------------------------------------------------------------------
// helpers
// ---------------------------------------------------------------------------
__device__ __forceinline__ float sgnf(float v) {
    return (v > 0.0f) ? 1.0f : ((v < 0.0f) ? -1.0f : 0.0f);
}

// Open3D ball->cube volume-preserving map, transcribed from the reference.
__device__ __forceinline__ void ball_to_cube(float x, float y, float z,
                                             float& X, float& Y, float& Z) {
    const float EPSF = 1e-12f;
    const float FOPI = (float)(4.0 / 3.14159265358979323846);
    float sq   = x * x + y * y + z * z;
    float norm = sqrtf(fmaxf(sq, EPSF));
    float rho2 = x * x + y * y;
    bool in_cone = (1.25f * z * z > rho2);
    float s1 = sqrtf(3.0f * norm / (norm + fabsf(z)));
    float s2 = norm / sqrtf(fmaxf(rho2, EPSF));
    float s  = in_cone ? s1 : s2;
    float xc = x * s;
    float yc = y * s;
    float zc = in_cone ? sgnf(z) * norm : 1.5f * z;
    if (sq < EPSF) { xc = 0.0f; yc = 0.0f; zc = 0.0f; }
    float sq_xy   = xc * xc + yc * yc;
    float norm_xy = sqrtf(fmaxf(sq_xy, EPSF));
    bool x_major = (fabsf(yc) <= fabsf(xc));
    float xd = (fabsf(xc) < EPSF) ? 1.0f : xc;
    float yd = (fabsf(yc) < EPSF) ? 1.0f : yc;
    float tx = sgnf(xc) * norm_xy;
    float ty = sgnf(yc) * norm_xy;
    float xq = x_major ? tx : ty * FOPI * atanf(xc / yd);
    float yq = x_major ? tx * FOPI * atanf(yc / xd) : ty;
    if (sq_xy < EPSF) { xq = 0.0f; yq = 0.0f; }
    X = xq; Y = yq; Z = zc;
}

// ---------------------------------------------------------------------------
// Kernel 1: per-(point,neighbor) geometry record + neighbor counts.
// Record (uint4): x,y,z = trilinear fracs (fp32 bits); w = packed:
//   [7:0]=c000 cell, [8]=dx?, [9]=dy?, [10]=dz?, [11]=valid, [25:12]=nidx
// ---------------------------------------------------------------------------
__global__ __launch_bounds__(256) void geom_kernel(
    const float* __restrict__ pos, const int* __restrict__ nidx,
    uint4* __restrict__ geo, float* __restrict__ cnt) {
    int t = blockIdx.x * 256 + threadIdx.x;
    if (t >= NPTS * KNB) return;
    int j = t >> 5;
    int k = t & 31;
    int nid = nidx[t];
    float px = pos[j * 3], py = pos[j * 3 + 1], pz = pos[j * 3 + 2];
    float qx = pos[nid * 3], qy = pos[nid * 3 + 1], qz = pos[nid * 3 + 2];
    // exact fp32 (no FMA contraction) to reproduce numpy's mask bit-for-bit
    float dx = __fsub_rn(px, qx), dy = __fsub_rn(py, qy), dz = __fsub_rn(pz, qz);
    float d2 = __fadd_rn(__fadd_rn(__fmul_rn(dx, dx), __fmul_rn(dy, dy)),
                         __fmul_rn(dz, dz));
    bool valid = (d2 <= 2.25f);
    if (valid && nid == 0) {
        for (int kk = 0; kk < k; ++kk) {
            if (nidx[j * KNB + kk] == 0) { valid = false; break; }
        }
    }
    uint4 g = make_uint4(0u, 0u, 0u, 0u);
    if (valid) {
        const float C = (float)(2.0 / 3.0);   // 2/EXTENT
        float ux = (qx - px) * C, uy = (qy - py) * C, uz = (qz - pz) * C;
        float X, Y, Z;
        ball_to_cube(ux, uy, uz, X, Y, Z);
        float cs[3] = { (X + 1.0f) * 2.5f, (Y + 1.0f) * 2.5f, (Z + 1.0f) * 2.5f };
        int i0[3], i1[3];
        float fr[3];
        #pragma unroll
        for (int d = 0; d < 3; ++d) {
            float f0 = floorf(cs[d]);
            fr[d] = cs[d] - f0;               // frac from UNCLIPPED floor (ref)
            int a = (int)f0;
            a = min(max(a, 0), 5);
            i0[d] = a;
            i1[d] = min(a + 1, 5);
        }
        int c000 = (i0[0] * 6 + i0[1]) * 6 + i0[2];
        unsigned bits = (unsigned)c000
                      | ((unsigned)(i1[0] - i0[0]) << 8)
                      | ((unsigned)(i1[1] - i0[1]) << 9)
                      | ((unsigned)(i1[2] - i0[2]) << 10)
                      | (1u << 11)
                      | ((unsigned)nid << 12);
        g.x = __float_as_uint(fr[0]);
        g.y = __float_as_uint(fr[1]);
        g.z = __float_as_uint(fr[2]);
        g.w = bits;
        atomicAdd(&cnt[j], 1.0f);
    }
    geo[t] = g;
}

// ---------------------------------------------------------------------------
// Kernel 2: counting sort of corner contributions by (CELL, PT) per 64-pt
// sort group (13824 buckets). Same-bucket contributions land ADJACENT ->
// the conv scatter can detect duplicates by neighbor-key compare and use
// plain ds_write for singletons. Payload: nid | ptl<<14 | cell<<20
// (y>>14 is the bucket key). starts[sg][217] = per-cell prefix.
// ---------------------------------------------------------------------------
__global__ __launch_bounds__(256) void sort_kernel(
    const uint4* __restrict__ geo, uint2* __restrict__ contribs,
    int* __restrict__ starts) {
    __shared__ int hist[13824];   // 216 cells * 64 pts
    __shared__ int part[257];
    const int sg = blockIdx.x, tid = threadIdx.x;
    for (int i = tid; i < 13824; i += 256) hist[i] = 0;
    __syncthreads();
    const int npts = min(64, NPTS - sg * 64);
    const int nrec = npts * KNB;
    const uint4* gb = geo + (size_t)sg * 64 * KNB;
    for (int r = tid; r < nrec; r += 256) {
        uint4 g = gb[r];
        if (g.w & 2048u) {
            int ptl = r >> 5;
            int c000 = g.w & 255u;
            int dxo = (g.w & 256u)  ? 36 : 0;
            int dyo = (g.w & 512u)  ? 6  : 0;
            int dzo = (g.w & 1024u) ? 1  : 0;
            #pragma unroll
            for (int c = 0; c < 8; ++c) {
                int cell = c000 + ((c & 4) ? dxo : 0) + ((c & 2) ? dyo : 0)
                                + ((c & 1) ? dzo : 0);
                atomicAdd(&hist[cell * 64 + ptl], 1);
            }
        }
    }
    __syncthreads();
    // exclusive scan of 13824 buckets: 256 threads x 54
    int sum = 0;
    for (int j = 0; j < 54; ++j) sum += hist[tid * 54 + j];
    part[tid] = sum;
    __syncthreads();
    if (tid == 0) {
        int run = 0;
        for (int i = 0; i < 256; ++i) { int v = part[i]; part[i] = run; run += v; }
        part[256] = run;
    }
    __syncthreads();
    {
        int run = part[tid];
        for (int j = 0; j < 54; ++j) {
            int i = tid * 54 + j;
            int v = hist[i]; hist[i] = run; run += v;
        }
    }
    __syncthreads();
    // per-cell starts (cell start = bucket (cell, pt=0) start)
    for (int i = tid; i < NCELL; i += 256)
        starts[sg * (NCELL + 1) + i] = hist[i * 64];
    if (tid == 0) starts[sg * (NCELL + 1) + NCELL] = part[256];
    __syncthreads();
    // scatter (fine cursors in hist)
    uint2* cb = contribs + (size_t)sg * 16384;
    for (int r = tid; r < nrec; r += 256) {
        uint4 g = gb[r];
        if (g.w & 2048u) {
            int ptl = r >> 5;
            float fx = __uint_as_float(g.x);
            float fy = __uint_as_float(g.y);
            float fz = __uint_as_float(g.z);
            int c000 = g.w & 255u;
            int dxo = (g.w & 256u)  ? 36 : 0;
            int dyo = (g.w & 512u)  ? 6  : 0;
            int dzo = (g.w & 1024u) ? 1  : 0;
            int nid = (g.w >> 12) & 16383u;
            #pragma unroll
            for (int c = 0; c < 8; ++c) {
                float wgt = ((c & 4) ? fx : 1.f - fx)
                          * ((c & 2) ? fy : 1.f - fy)
                          * ((c & 1) ? fz : 1.f - fz);
                int cell = c000 + ((c & 4) ? dxo : 0) + ((c & 2) ? dyo : 0)
                                + ((c & 1) ? dzo : 0);
                int p = atomicAdd(&hist[cell * 64 + ptl], 1);
                cb[p] = make_uint2(__float_as_uint(wgt),
                                   (unsigned)nid | ((unsigned)ptl << 14)
                                                 | ((unsigned)cell << 20));
            }
        }
    }
}

// ---------------------------------------------------------------------------
// Kernel 3: conv, two-phase per chunk, all 4 waves in both phases.
// Block = 256 thr, one 64-pt sort group, all COUT outputs.
//   scatter: slot = CIN/4 threads per contribution, U=4 batched (all rec +
//     neighbor-key + feats loads issue before use). (cell,pt)-sorted stream
//     => duplicates adjacent: singleton buckets use ONE ds_write_b128,
//     duplicates fall back to ds atomics (zeroed tile). This removes the
//     4x ds_add RMW per contribution that R3-R8 paid.
//   GEMM: thread (cog=tid%8, ptg=tid/8) owns 2pts x CO_T cos; A rows
//     ptg+p*32 (adjacent lanes adjacent banks -> conflict-free b128);
//     W from global (L1/L2-resident).
// 4 blocks/CU (18 KB LDS): phases of different blocks interleave on the CU.
// K-split over blockIdx.y into partial buffers (combined later).
// ---------------------------------------------------------------------------
template<int CIN, int COUT, int CPC, int KSPLIT, int CO_T>
__global__ __launch_bounds__(256, 4) void conv_kernel(
    const float* __restrict__ feats, const float* __restrict__ W,
    const uint2* __restrict__ contribs, const int* __restrict__ starts,
    float* __restrict__ partial) {
    constexpr int KC    = CPC * CIN;      // K per chunk (32 or 64)
    constexpr int AQ    = KC / 4 + 1;     // row stride in float4 (odd)
    constexpr int NCHUNK = NCELL / CPC;
    constexpr int NCOG  = COUT / CO_T;    // 8
    constexpr int NPTG  = 256 / NCOG;     // 32
    constexpr int PT_PER = 64 / NPTG;     // 2
    constexpr int Q4    = CO_T / 4;       // 2 or 1
    constexpr int TPC   = CIN / 4;        // threads per contribution
    constexpr int NSLOT = 256 / TPC;
    constexpr int U     = 4;

    __shared__ float4 A4[64 * AQ];
    __shared__ int Sl[NCELL + 1];

    const int tid  = threadIdx.x;
    const int bx   = blockIdx.x;          // sort group
    const int ks   = blockIdx.y;
    const int cog  = tid % NCOG;
    const int ptg  = tid / NCOG;
    const int slot = tid / TPC;
    const int ch   = tid % TPC;
    const uint2* cbs = contribs + (size_t)bx * 16384;

    for (int i = tid; i < NCELL + 1; i += 256)
        Sl[i] = starts[bx * (NCELL + 1) + i];

    const int c0 = NCHUNK * ks / KSPLIT;
    const int c1 = NCHUNK * (ks + 1) / KSPLIT;

    float4 acc[PT_PER][Q4];
    #pragma unroll
    for (int p = 0; p < PT_PER; ++p)
        #pragma unroll
        for (int q = 0; q < Q4; ++q)
            acc[p][q] = make_float4(0.f, 0.f, 0.f, 0.f);

    for (int c = c0; c < c1; ++c) {
        // ---- zero A tile ----
        {
            float4 z = make_float4(0.f, 0.f, 0.f, 0.f);
            for (int i = tid; i < 64 * AQ; i += 256) A4[i] = z;
        }
        __syncthreads();                  // also publishes Sl on first pass
        // ---- scatter ----
        const int cb = c * CPC;
        const int s = Sl[cb], e = Sl[cb + CPC];
        float* A = reinterpret_cast<float*>(A4);
        for (int it = s + slot; it < e; it += U * NSLOT) {
            uint2 recs[U]; unsigned pv[U], nx[U]; float4 f4[U];
            #pragma unroll
            for (int u = 0; u < U; ++u) {
                int idx = min(it + u * NSLOT, e - 1);
                recs[u] = cbs[idx];
                pv[u] = (idx > 0) ? cbs[idx - 1].y : 0xFFFFFFFFu;
                nx[u] = cbs[idx + 1].y;   // next sg region / starts: allocated
            }
            #pragma unroll
            for (int u = 0; u < U; ++u)
                f4[u] = *reinterpret_cast<const float4*>(
                    feats + (size_t)(recs[u].y & 16383) * CIN + ch * 4);
            #pragma unroll
            for (int u = 0; u < U; ++u) {
                int idx = it + u * NSLOT;
                if (idx < e) {
                    unsigned y = recs[u].y;
                    unsigned key = y >> 14;           // pt | cell<<6
                    bool dup = ((pv[u] >> 14) == key) || ((nx[u] >> 14) == key);
                    float wgt = __uint_as_float(recs[u].x);
                    int ptl = (int)(key & 63u);
                    int cel = (int)(y >> 20);
                    float* dst = A + ptl * (AQ * 4) + (cel - cb) * CIN + ch * 4;
                    float vx = wgt * f4[u].x, vy = wgt * f4[u].y;
                    float vz = wgt * f4[u].z, vw = wgt * f4[u].w;
                    if (!dup) {
                        *reinterpret_cast<float4*>(dst) = make_float4(vx, vy, vz, vw);
                    } else {
                        atomicAdd(dst + 0, vx);
                        atomicAdd(dst + 1, vy);
                        atomicAdd(dst + 2, vz);
                        atomicAdd(dst + 3, vw);
                    }
                }
            }
        }
        __syncthreads();
        // ---- GEMM ----
        const float* Wc = W + (size_t)c * KC * COUT + cog * CO_T;
        #pragma unroll 2
        for (int g = 0; g < KC / 4; ++g) {
            float4 wv[4][Q4];
            #pragma unroll
            for (int j = 0; j < 4; ++j) {
                const float* wp = Wc + (size_t)(g * 4 + j) * COUT;
                #pragma unroll
                for (int q = 0; q < Q4; ++q)
                    wv[j][q] = *reinterpret_cast<const float4*>(wp + q * 4);
            }
            float4 av[PT_PER];
            #pragma unroll
            for (int p = 0; p < PT_PER; ++p)
                av[p] = A4[(ptg + p * NPTG) * AQ + g];   // conflict-free b128
            #pragma unroll
            for (int p = 0; p < PT_PER; ++p) {
                const float* ap = reinterpret_cast<const float*>(&av[p]);
                #pragma unroll
                for (int j = 0; j < 4; ++j) {
                    float a = ap[j];
                    #pragma unroll
                    for (int q = 0; q < Q4; ++q) {
                        acc[p][q].x = fmaf(a, wv[j][q].x, acc[p][q].x);
                        acc[p][q].y = fmaf(a, wv[j][q].y, acc[p][q].y);
                        acc[p][q].z = fmaf(a, wv[j][q].z, acc[p][q].z);
                        acc[p][q].w = fmaf(a, wv[j][q].w, acc[p][q].w);
                    }
                }
            }
        }
        __syncthreads();
    }

    #pragma unroll
    for (int p = 0; p < PT_PER; ++p) {
        int n = bx * 64 + ptg + p * NPTG;
        if (n < NPTS) {
            float* po = partial + ((size_t)ks * NPTS + n) * COUT + cog * CO_T;
            #pragma unroll
            for (int q = 0; q < Q4; ++q)
                *reinterpret_cast<float4*>(po + q * 4) = acc[p][q];
        }
    }
}

// ---------------------------------------------------------------------------
// Kernel 4: combine K-split partials, normalize by neighbor count, bias, relu.
// ---------------------------------------------------------------------------
template<int COUT, int KSPLIT>
__global__ __launch_bounds__(256) void combine_kernel(
    const float* __restrict__ partial, const float* __restrict__ cnt,
    const float* __restrict__ bias, float* __restrict__ out) {
    int idx = blockIdx.x * 256 + threadIdx.x;
    if (idx >= NPTS * COUT) return;
    int n = idx / COUT, co = idx % COUT;
    float s = 0.f;
    #pragma unroll
    for (int k2 = 0; k2 < KSPLIT; ++k2)
        s += partial[((size_t)k2 * NPTS + n) * COUT + co];
    float c = cnt[n];
    if (c > 0.f) s /= fmaxf(c, 1.f);
    out[idx] = fmaxf(s + bias[co], 0.f);
}

// ---------------------------------------------------------------------------
// Kernel 5: fused FC chain. One wave per point, __shfl broadcasts.
// ---------------------------------------------------------------------------
__global__ __launch_bounds__(64) void fc_kernel(
    const float* __restrict__ x,
    const float* __restrict__ W1, const float* __restrict__ b1,
    const float* __restrict__ W2, const float* __restrict__ b2,
    const float* __restrict__ W3, const float* __restrict__ b3,
    const float* __restrict__ W4, const float* __restrict__ b4,
    float* __restrict__ out) {
    int n = blockIdx.x;
    int lane = threadIdx.x;
    float xv = (lane < 32) ? x[(size_t)n * 32 + lane] : 0.0f;

    float t = b1[lane];
    for (int ci = 0; ci < 32; ++ci)
        t = fmaf(__shfl(xv, ci), W1[ci * 64 + lane], t);
    float h1 = fmaxf(t, 0.0f);

    t = b2[lane];
    for (int ci = 0; ci < 64; ++ci)
        t = fmaf(__shfl(h1, ci), W2[ci * 64 + lane], t);
    float h2 = fmaxf(t, 0.0f);

    int l32 = lane & 31;
    t = b3[l32];
    for (int ci = 0; ci < 64; ++ci)
        t = fmaf(__shfl(h2, ci), W3[ci * 32 + l32], t);
    float h3 = fmaxf(t, 0.0f);

    int ch = (lane < 3) ? lane : 0;
    float o = b4[ch];
    for (int ci = 0; ci < 32; ++ci)
        o = fmaf(__shfl(h3, ci), W4[ci * 3 + ch], o);
    if (lane < 3) out[(size_t)n * 3 + lane] = o;
}

// ---------------------------------------------------------------------------
// launch
// ---------------------------------------------------------------------------
extern "C" void kernel_launch(void* const* d_in, const int* in_sizes, int n_in,
                              void* d_out, int out_size, void* d_ws, size_t ws_size,
                              hipStream_t stream) {
    const float* feats = (const float*)d_in[0];
    const float* pos   = (const float*)d_in[1];
    const int*   nidx  = (const int*)d_in[2];
    // d_in[3] (neighbor_mask) unused: mask recomputed exactly.
    const float* W1 = (const float*)d_in[4];
    const float* b1 = (const float*)d_in[5];
    const float* W2 = (const float*)d_in[6];
    const float* b2 = (const float*)d_in[7];
    const float* W3 = (const float*)d_in[8];
    const float* b3 = (const float*)d_in[9];
    const float* Wfc1 = (const float*)d_in[10];
    const float* bfc1 = (const float*)d_in[11];
    const float* Wfc2 = (const float*)d_in[12];
    const float* bfc2 = (const float*)d_in[13];
    const float* Wfc3 = (const float*)d_in[14];
    const float* bfc3 = (const float*)d_in[15];
    const float* Wout = (const float*)d_in[16];
    const float* bout = (const float*)d_in[17];

    char* ws = (char*)d_ws;
    uint2* contrib = (uint2*)(ws);                    // 20,578,304 B
    int*   starts  = (int*)  (ws + 20578304);         //    136,276 B
    float* cnt     = (float*)(ws + 20714624);         //     40,000 B
    float* x1      = (float*)(ws + 20754624);         //  2,560,000 B
    float* x2      = (float*)(ws + 23314624);         //  2,560,000 B
    float* x3      = (float*)(ws + 25874624);         //  1,280,000 B
    // geo (5.12 MB) dead after sort -> alias with partial region
    uint4* geo     = (uint4*)(ws + 27154624);
    float* partial = (float*)(ws + 27154624);         // 10.24 MB base region

    // big: conv2 KSPLIT=6 needs 6 * 2.56 MB = 15.36 MB partial region
    const bool big = ws_size >= (size_t)(27154624 + 6 * 2560000);

    hipMemsetAsync(cnt, 0, NPTS * sizeof(float), stream);
    geom_kernel<<<(NPTS * KNB) / 256, 256, 0, stream>>>(pos, nidx, geo, cnt);
    sort_kernel<<<NSGT, 256, 0, stream>>>(geo, contrib, starts);

    // conv1: CIN=4, COUT=64, CPC=8 (KC=32), KSPLIT=4, CO_T=8
    conv_kernel<4, 64, 8, 4, 8><<<dim3(NSGT, 4), 256, 0, stream>>>(
        feats, W1, contrib, starts, partial);
    combine_kernel<64, 4><<<(NPTS * 64 + 255) / 256, 256, 0, stream>>>(
        partial, cnt, b1, x1);

    // conv2: CIN=64, COUT=64, CPC=1 (KC=64), CO_T=8
    if (big) {
        conv_kernel<64, 64, 1, 6, 8><<<dim3(NSGT, 6), 256, 0, stream>>>(
            x1, W2, contrib, starts, partial);
        combine_kernel<64, 6><<<(NPTS * 64 + 255) / 256, 256, 0, stream>>>(
            partial, cnt, b2, x2);
    } else {
        conv_kernel<64, 64, 1, 4, 8><<<dim3(NSGT, 4), 256, 0, stream>>>(
            x1, W2, contrib, starts, partial);
        combine_kernel<64, 4><<<(NPTS * 64 + 255) / 256, 256, 0, stream>>>(
            partial, cnt, b2, x2);
    }

    // conv3: CIN=64, COUT=32, CPC=1, KSPLIT=6, CO_T=4 (partial 7.68 MB)
    conv_kernel<64, 32, 1, 6, 4><<<dim3(NSGT, 6), 256, 0, stream>>>(
        x2, W3, contrib, starts, partial);
    combine_kernel<32, 6><<<(NPTS * 32 + 255) / 256, 256, 0, stream>>>(
        partial, cnt, b3, x3);

    fc_kernel<<<NPTS, 64, 0, stream>>>(x3, Wfc1, bfc1, Wfc2, bfc2,
                                       Wfc3, bfc3, Wout, bout, (float*)d_out);
}